// Round 3
// baseline (561.164 us; speedup 1.0000x reference)
//
#include <hip/hip_runtime.h>
#include <hip/hip_bf16.h>

#define B_DIM 8192
#define D_DIM 2048
#define U_DIM 2048
#define KWORDS 64            // 2048 bits = 64 uint32 words per row/col
#define CWORDS 32            // words per K-chunk (2 chunks)

// ---------------- Kernel 1: pack input signs via wave ballot ----------------
__global__ void pack_x_kernel(const float* __restrict__ x,
                              unsigned long long* __restrict__ xb) {
    const int gwave = (blockIdx.x * blockDim.x + threadIdx.x) >> 6;
    const int lane  = threadIdx.x & 63;
    const size_t base = (size_t)gwave * 256;
    float v0 = x[base + lane];
    float v1 = x[base + 64 + lane];
    float v2 = x[base + 128 + lane];
    float v3 = x[base + 192 + lane];
    unsigned long long m0 = __ballot(v0 >= 0.0f);
    unsigned long long m1 = __ballot(v1 >= 0.0f);
    unsigned long long m2 = __ballot(v2 >= 0.0f);
    unsigned long long m3 = __ballot(v3 >= 0.0f);
    if (lane == 0) {
        ulonglong2* p = (ulonglong2*)(xb + (base >> 6));
        ulonglong2 a; a.x = m0; a.y = m1;
        ulonglong2 b; b.x = m2; b.y = m3;
        p[0] = a;
        p[1] = b;
    }
}

// ---------------- Kernel 2: pack kernel signs (transposed) ----------------
__global__ void pack_k_kernel(const float* __restrict__ k,
                              unsigned long long* __restrict__ kb) {
    __shared__ float tile[64][65];
    const int j0 = (blockIdx.x & 31) * 64;
    const int d0 = (blockIdx.x >> 5) * 64;
    const int tid  = threadIdx.x;
    const int lane = tid & 63;
    const int wv   = tid >> 6;

    for (int i = 0; i < 16; i++) {
        int row = i * 4 + wv;
        tile[row][lane] = k[(size_t)(d0 + row) * U_DIM + j0 + lane];
    }
    __syncthreads();

    for (int c = wv * 16; c < wv * 16 + 16; c++) {
        float v = tile[lane][c];
        unsigned long long m = __ballot(v >= 0.0f);
        if (lane == 0) kb[(size_t)(j0 + c) * (D_DIM / 64) + (d0 >> 6)] = m;
    }
}

// ---------------- Kernel 3: binary GEMM via xor + popcount ----------------
// out[i][j] = D - 2*popc(xbits[i] ^ kbits[j]) + bias[j]
// 128x128 tile, 256 threads, 8x8 per thread. K staged in 2 chunks of 32 words
// -> 32KB LDS total -> 4 blocks/CU (16 waves, the VGPR-128 occupancy cap).
// XOR swizzle (group g of row r at g^((r>>3)&7)) keeps fragment reads
// broadcast/2-way (free).
__launch_bounds__(256, 4)
__global__ void bgemm_kernel(const unsigned int* __restrict__ xb,   // [B][64]
                             const unsigned int* __restrict__ kb,   // [U][64]
                             const float* __restrict__ bias,
                             float* __restrict__ out) {
    __shared__ unsigned int xs[128 * CWORDS];   // 16KB
    __shared__ unsigned int ks[128 * CWORDS];   // 16KB

    const int bx  = blockIdx.x;
    const int by  = blockIdx.y;
    const int tid = threadIdx.x;

    const uint4* xsrc = (const uint4*)(xb + (size_t)(by * 128) * KWORDS);
    const uint4* ksrc = (const uint4*)(kb + (size_t)(bx * 128) * KWORDS);

    const int tr  = (tid >> 4) * 8;        // thread's 8 rows
    const int tc  = (tid & 15) * 8;        // thread's 8 cols
    const int xsw = (tid >> 4) & 7;
    const int ksw = tid & 7;
    int acc[8][8] = {};

    for (int ch = 0; ch < 2; ch++) {
        if (ch) __syncthreads();           // LDS reuse: wait for prev compute
#pragma unroll
        for (int i = 0; i < 4; i++) {
            int flat = tid + i * 256;      // 0..1023 uint4 slots per array
            int r    = flat >> 3;          // 8 uint4 per 32-word chunk row
            int g    = flat & 7;
            int sg   = g ^ ((r >> 3) & 7);
            uint4 xv = xsrc[r * 16 + ch * 8 + g];
            uint4 kv = ksrc[r * 16 + ch * 8 + g];
            *((uint4*)&xs[r * CWORDS + sg * 4]) = xv;
            *((uint4*)&ks[r * CWORDS + sg * 4]) = kv;
        }
        __syncthreads();

#pragma unroll 2
        for (int w4 = 0; w4 < 8; w4++) {
            uint4 xv[8], kv[8];
            const int xcol = (w4 ^ xsw) * 4;
            const int kcol = (w4 ^ ksw) * 4;
#pragma unroll
            for (int r = 0; r < 8; r++) xv[r] = *((const uint4*)&xs[(tr + r) * CWORDS + xcol]);
#pragma unroll
            for (int c = 0; c < 8; c++) kv[c] = *((const uint4*)&ks[(tc + c) * CWORDS + kcol]);
#pragma unroll
            for (int r = 0; r < 8; r++)
#pragma unroll
                for (int c = 0; c < 8; c++) {
                    acc[r][c] += __popc(xv[r].x ^ kv[c].x);
                    acc[r][c] += __popc(xv[r].y ^ kv[c].y);
                    acc[r][c] += __popc(xv[r].z ^ kv[c].z);
                    acc[r][c] += __popc(xv[r].w ^ kv[c].w);
                }
        }
    }

    const int row0 = by * 128 + tr;
    const int col0 = bx * 128 + tc;
    const float4 b0 = *((const float4*)&bias[col0]);
    const float4 b1 = *((const float4*)&bias[col0 + 4]);
#pragma unroll
    for (int r = 0; r < 8; r++) {
        float4 o0, o1;
        o0.x = (float)(D_DIM - 2 * acc[r][0]) + b0.x;
        o0.y = (float)(D_DIM - 2 * acc[r][1]) + b0.y;
        o0.z = (float)(D_DIM - 2 * acc[r][2]) + b0.z;
        o0.w = (float)(D_DIM - 2 * acc[r][3]) + b0.w;
        o1.x = (float)(D_DIM - 2 * acc[r][4]) + b1.x;
        o1.y = (float)(D_DIM - 2 * acc[r][5]) + b1.y;
        o1.z = (float)(D_DIM - 2 * acc[r][6]) + b1.z;
        o1.w = (float)(D_DIM - 2 * acc[r][7]) + b1.w;
        float* orow = &out[(size_t)(row0 + r) * U_DIM + col0];
        *((float4*)orow)       = o0;
        *((float4*)(orow + 4)) = o1;
    }
}

extern "C" void kernel_launch(void* const* d_in, const int* in_sizes, int n_in,
                              void* d_out, int out_size, void* d_ws, size_t ws_size,
                              hipStream_t stream) {
    const float* x    = (const float*)d_in[0];   // [8192][2048]
    const float* k    = (const float*)d_in[1];   // [2048][2048]
    const float* bias = (const float*)d_in[2];   // [2048]
    float* out = (float*)d_out;

    unsigned long long* xbits = (unsigned long long*)d_ws;                       // 2 MB
    unsigned long long* kbits = (unsigned long long*)((char*)d_ws + (size_t)B_DIM * (D_DIM / 8)); // 0.5 MB

    pack_x_kernel<<<(B_DIM * D_DIM) / 1024, 256, 0, stream>>>(x, xbits);
    pack_k_kernel<<<32 * 32, 256, 0, stream>>>(k, kbits);
    dim3 grid(U_DIM / 128, B_DIM / 128);
    bgemm_kernel<<<grid, 256, 0, stream>>>((const unsigned int*)xbits,
                                           (const unsigned int*)kbits, bias, out);
}

// Round 4
// 202.935 us; speedup vs baseline: 2.7652x; 2.7652x over previous
//
#include <hip/hip_runtime.h>
#include <hip/hip_bf16.h>

#define B_DIM 8192
#define D_DIM 2048
#define U_DIM 2048
#define KWORDS 64            // 2048 bits = 64 uint32 words per row/col
#define CWORDS 32            // words per K-chunk (2 chunks)

// ---------------- Kernel 1: pack input signs via wave ballot ----------------
__global__ void pack_x_kernel(const float* __restrict__ x,
                              unsigned long long* __restrict__ xb) {
    const int gwave = (blockIdx.x * blockDim.x + threadIdx.x) >> 6;
    const int lane  = threadIdx.x & 63;
    const size_t base = (size_t)gwave * 256;
    float v0 = x[base + lane];
    float v1 = x[base + 64 + lane];
    float v2 = x[base + 128 + lane];
    float v3 = x[base + 192 + lane];
    unsigned long long m0 = __ballot(v0 >= 0.0f);
    unsigned long long m1 = __ballot(v1 >= 0.0f);
    unsigned long long m2 = __ballot(v2 >= 0.0f);
    unsigned long long m3 = __ballot(v3 >= 0.0f);
    if (lane == 0) {
        ulonglong2* p = (ulonglong2*)(xb + (base >> 6));
        ulonglong2 a; a.x = m0; a.y = m1;
        ulonglong2 b; b.x = m2; b.y = m3;
        p[0] = a;
        p[1] = b;
    }
}

// ---------------- Kernel 2: pack kernel signs (transposed) ----------------
__global__ void pack_k_kernel(const float* __restrict__ k,
                              unsigned long long* __restrict__ kb) {
    __shared__ float tile[64][65];
    const int j0 = (blockIdx.x & 31) * 64;
    const int d0 = (blockIdx.x >> 5) * 64;
    const int tid  = threadIdx.x;
    const int lane = tid & 63;
    const int wv   = tid >> 6;

    for (int i = 0; i < 16; i++) {
        int row = i * 4 + wv;
        tile[row][lane] = k[(size_t)(d0 + row) * U_DIM + j0 + lane];
    }
    __syncthreads();

    for (int c = wv * 16; c < wv * 16 + 16; c++) {
        float v = tile[lane][c];
        unsigned long long m = __ballot(v >= 0.0f);
        if (lane == 0) kb[(size_t)(j0 + c) * (D_DIM / 64) + (d0 >> 6)] = m;
    }
}

// ---------------- Kernel 3: binary GEMM via xor + popcount ----------------
// out[i][j] = D - 2*popc(xbits[i] ^ kbits[j]) + bias[j]
// 128x128 tile, 256 threads, 8x8 per thread. K staged in 2 chunks of 32 words
// -> 32KB LDS total. XOR swizzle keeps fragment reads broadcast/2-way (free).
//
// __launch_bounds__(256, 2): R3's (256,4) pushed the allocator into the
// 64-VGPR band and spilled acc[8][8] to scratch (FETCH 669MB / WRITE 1.3GB).
// (256,2) compiles this structure to exactly 128 VGPRs (verified R2) ->
// HW-derived occupancy: 128 VGPR = 4 waves/EU, 32KB LDS = 5 blocks -> 4 blocks/CU.
__launch_bounds__(256, 2)
__global__ void bgemm_kernel(const unsigned int* __restrict__ xb,   // [B][64]
                             const unsigned int* __restrict__ kb,   // [U][64]
                             const float* __restrict__ bias,
                             float* __restrict__ out) {
    __shared__ unsigned int xs[128 * CWORDS];   // 16KB
    __shared__ unsigned int ks[128 * CWORDS];   // 16KB

    const int bx  = blockIdx.x;
    const int by  = blockIdx.y;
    const int tid = threadIdx.x;

    const uint4* xsrc = (const uint4*)(xb + (size_t)(by * 128) * KWORDS);
    const uint4* ksrc = (const uint4*)(kb + (size_t)(bx * 128) * KWORDS);

    const int tr  = (tid >> 4) * 8;        // thread's 8 rows
    const int tc  = (tid & 15) * 8;        // thread's 8 cols
    const int xsw = (tid >> 4) & 7;
    const int ksw = tid & 7;
    int acc[8][8] = {};

    for (int ch = 0; ch < 2; ch++) {
        if (ch) __syncthreads();           // LDS reuse: wait for prev compute
#pragma unroll
        for (int i = 0; i < 4; i++) {
            int flat = tid + i * 256;      // 0..1023 uint4 slots per array
            int r    = flat >> 3;          // 8 uint4 per 32-word chunk row
            int g    = flat & 7;
            int sg   = g ^ ((r >> 3) & 7);
            uint4 xv = xsrc[r * 16 + ch * 8 + g];
            uint4 kv = ksrc[r * 16 + ch * 8 + g];
            *((uint4*)&xs[r * CWORDS + sg * 4]) = xv;
            *((uint4*)&ks[r * CWORDS + sg * 4]) = kv;
        }
        __syncthreads();

        for (int w4 = 0; w4 < 8; w4++) {
            uint4 xv[8], kv[8];
            const int xcol = (w4 ^ xsw) * 4;
            const int kcol = (w4 ^ ksw) * 4;
#pragma unroll
            for (int r = 0; r < 8; r++) xv[r] = *((const uint4*)&xs[(tr + r) * CWORDS + xcol]);
#pragma unroll
            for (int c = 0; c < 8; c++) kv[c] = *((const uint4*)&ks[(tc + c) * CWORDS + kcol]);
#pragma unroll
            for (int r = 0; r < 8; r++)
#pragma unroll
                for (int c = 0; c < 8; c++) {
                    acc[r][c] += __popc(xv[r].x ^ kv[c].x);
                    acc[r][c] += __popc(xv[r].y ^ kv[c].y);
                    acc[r][c] += __popc(xv[r].z ^ kv[c].z);
                    acc[r][c] += __popc(xv[r].w ^ kv[c].w);
                }
        }
    }

    const int row0 = by * 128 + tr;
    const int col0 = bx * 128 + tc;
    const float4 b0 = *((const float4*)&bias[col0]);
    const float4 b1 = *((const float4*)&bias[col0 + 4]);
#pragma unroll
    for (int r = 0; r < 8; r++) {
        float4 o0, o1;
        o0.x = (float)(D_DIM - 2 * acc[r][0]) + b0.x;
        o0.y = (float)(D_DIM - 2 * acc[r][1]) + b0.y;
        o0.z = (float)(D_DIM - 2 * acc[r][2]) + b0.z;
        o0.w = (float)(D_DIM - 2 * acc[r][3]) + b0.w;
        o1.x = (float)(D_DIM - 2 * acc[r][4]) + b1.x;
        o1.y = (float)(D_DIM - 2 * acc[r][5]) + b1.y;
        o1.z = (float)(D_DIM - 2 * acc[r][6]) + b1.z;
        o1.w = (float)(D_DIM - 2 * acc[r][7]) + b1.w;
        float* orow = &out[(size_t)(row0 + r) * U_DIM + col0];
        *((float4*)orow)       = o0;
        *((float4*)(orow + 4)) = o1;
    }
}

extern "C" void kernel_launch(void* const* d_in, const int* in_sizes, int n_in,
                              void* d_out, int out_size, void* d_ws, size_t ws_size,
                              hipStream_t stream) {
    const float* x    = (const float*)d_in[0];   // [8192][2048]
    const float* k    = (const float*)d_in[1];   // [2048][2048]
    const float* bias = (const float*)d_in[2];   // [2048]
    float* out = (float*)d_out;

    unsigned long long* xbits = (unsigned long long*)d_ws;                       // 2 MB
    unsigned long long* kbits = (unsigned long long*)((char*)d_ws + (size_t)B_DIM * (D_DIM / 8)); // 0.5 MB

    pack_x_kernel<<<(B_DIM * D_DIM) / 1024, 256, 0, stream>>>(x, xbits);
    pack_k_kernel<<<32 * 32, 256, 0, stream>>>(k, kbits);
    dim3 grid(U_DIM / 128, B_DIM / 128);
    bgemm_kernel<<<grid, 256, 0, stream>>>((const unsigned int*)xbits,
                                           (const unsigned int*)kbits, bias, out);
}

// Round 5
// 186.230 us; speedup vs baseline: 3.0133x; 1.0897x over previous
//
#include <hip/hip_runtime.h>
#include <hip/hip_bf16.h>

#define B_DIM 8192
#define D_DIM 2048
#define U_DIM 2048
#define KWORDS 64            // 2048 bits = 64 uint32 words per row/col

// Fused popcount-accumulate: D = popc(S0) + D, exactly 1 VALU instr.
// Compiler was emitting v_bcnt + separate v_add (3 instr/MAC); this pins 2.
__device__ __forceinline__ void bcnt_acc(unsigned int v, int& acc) {
    asm("v_bcnt_u32_b32 %0, %1, %0" : "+v"(acc) : "v"(v));
}

// ---------------- Kernel 1: pack input signs via wave ballot ----------------
__global__ void pack_x_kernel(const float* __restrict__ x,
                              unsigned long long* __restrict__ xb) {
    const int gwave = (blockIdx.x * blockDim.x + threadIdx.x) >> 6;
    const int lane  = threadIdx.x & 63;
    const size_t base = (size_t)gwave * 256;
    float v0 = x[base + lane];
    float v1 = x[base + 64 + lane];
    float v2 = x[base + 128 + lane];
    float v3 = x[base + 192 + lane];
    unsigned long long m0 = __ballot(v0 >= 0.0f);
    unsigned long long m1 = __ballot(v1 >= 0.0f);
    unsigned long long m2 = __ballot(v2 >= 0.0f);
    unsigned long long m3 = __ballot(v3 >= 0.0f);
    if (lane == 0) {
        ulonglong2* p = (ulonglong2*)(xb + (base >> 6));
        ulonglong2 a; a.x = m0; a.y = m1;
        ulonglong2 b; b.x = m2; b.y = m3;
        p[0] = a;
        p[1] = b;
    }
}

// ---------------- Kernel 2: pack kernel signs (transposed) ----------------
__global__ void pack_k_kernel(const float* __restrict__ k,
                              unsigned long long* __restrict__ kb) {
    __shared__ float tile[64][65];
    const int j0 = (blockIdx.x & 31) * 64;
    const int d0 = (blockIdx.x >> 5) * 64;
    const int tid  = threadIdx.x;
    const int lane = tid & 63;
    const int wv   = tid >> 6;

    for (int i = 0; i < 16; i++) {
        int row = i * 4 + wv;
        tile[row][lane] = k[(size_t)(d0 + row) * U_DIM + j0 + lane];
    }
    __syncthreads();

    for (int c = wv * 16; c < wv * 16 + 16; c++) {
        float v = tile[lane][c];
        unsigned long long m = __ballot(v >= 0.0f);
        if (lane == 0) kb[(size_t)(j0 + c) * (D_DIM / 64) + (d0 >> 6)] = m;
    }
}

// ---------------- Kernel 3: binary GEMM via xor + popcount ----------------
// out[i][j] = D - 2*popc(xbits[i] ^ kbits[j]) + bias[j]
// 128x128 tile, 512 threads, 4 rows x 8 cols per thread.
// Whole-K resident (2x32KB LDS), SINGLE barrier -> no per-chunk drains.
// ~100 VGPR (acc 32 + frags 48) -> real 4 waves/SIMD; 64KB LDS -> 2 blocks/CU
// -> 16 waves/CU. XOR swizzle: word-group g of row r at g^((r>>3)&7);
// fragment reads hit each bank group with 2 addresses max (free).
__launch_bounds__(512)
__global__ void bgemm_kernel(const unsigned int* __restrict__ xb,   // [B][64]
                             const unsigned int* __restrict__ kb,   // [U][64]
                             const float* __restrict__ bias,
                             float* __restrict__ out) {
    __shared__ unsigned int xs[128 * KWORDS];   // 32KB
    __shared__ unsigned int ks[128 * KWORDS];   // 32KB

    const int bx  = blockIdx.x;
    const int by  = blockIdx.y;
    const int tid = threadIdx.x;               // 0..511

    const uint4* xsrc = (const uint4*)(xb + (size_t)(by * 128) * KWORDS);
    const uint4* ksrc = (const uint4*)(kb + (size_t)(bx * 128) * KWORDS);

    // Stage both 32KB tiles: 2048 uint4 each, 512 threads x 4. Coalesced.
#pragma unroll
    for (int i = 0; i < 4; i++) {
        int flat = tid + i * 512;              // 0..2047
        int r    = flat >> 4;                  // 16 uint4 per row
        int g    = flat & 15;
        int sg   = g ^ ((r >> 3) & 7);
        uint4 xv = xsrc[flat];
        uint4 kv = ksrc[flat];
        *((uint4*)&xs[r * KWORDS + sg * 4]) = xv;
        *((uint4*)&ks[r * KWORDS + sg * 4]) = kv;
    }
    __syncthreads();                           // the only barrier

    const int tr  = (tid >> 4) * 4;            // 4 rows  (tr%8 in {0,4}: all share r>>3)
    const int tc  = (tid & 15) * 8;            // 8 cols  (all share c>>3 = tid&15)
    const int xsw = (tr >> 4) & 7;             // == (row>>3)&7 for rows tr..tr+3? see below
    const int xswz = ((tid >> 4) >> 1) & 7;    // rows tr..tr+3 -> r>>3 = (tid>>4)>>1
    const int ksw = tid & 7;                   // (tid&15)&7
    int acc[4][8] = {};

    for (int w4 = 0; w4 < 16; w4++) {
        const int xcol = (w4 ^ xswz) * 4;
        const int kcol = (w4 ^ ksw) * 4;
        uint4 xv[4], kv[8];
#pragma unroll
        for (int r = 0; r < 4; r++) xv[r] = *((const uint4*)&xs[(tr + r) * KWORDS + xcol]);
#pragma unroll
        for (int c = 0; c < 8; c++) kv[c] = *((const uint4*)&ks[(tc + c) * KWORDS + kcol]);
#pragma unroll
        for (int r = 0; r < 4; r++)
#pragma unroll
            for (int c = 0; c < 8; c++) {
                bcnt_acc(xv[r].x ^ kv[c].x, acc[r][c]);
                bcnt_acc(xv[r].y ^ kv[c].y, acc[r][c]);
                bcnt_acc(xv[r].z ^ kv[c].z, acc[r][c]);
                bcnt_acc(xv[r].w ^ kv[c].w, acc[r][c]);
            }
    }
    (void)xsw;

    const int row0 = by * 128 + tr;
    const int col0 = bx * 128 + tc;
    const float4 b0 = *((const float4*)&bias[col0]);
    const float4 b1 = *((const float4*)&bias[col0 + 4]);
#pragma unroll
    for (int r = 0; r < 4; r++) {
        float4 o0, o1;
        o0.x = (float)(D_DIM - 2 * acc[r][0]) + b0.x;
        o0.y = (float)(D_DIM - 2 * acc[r][1]) + b0.y;
        o0.z = (float)(D_DIM - 2 * acc[r][2]) + b0.z;
        o0.w = (float)(D_DIM - 2 * acc[r][3]) + b0.w;
        o1.x = (float)(D_DIM - 2 * acc[r][4]) + b1.x;
        o1.y = (float)(D_DIM - 2 * acc[r][5]) + b1.y;
        o1.z = (float)(D_DIM - 2 * acc[r][6]) + b1.z;
        o1.w = (float)(D_DIM - 2 * acc[r][7]) + b1.w;
        float* orow = &out[(size_t)(row0 + r) * U_DIM + col0];
        *((float4*)orow)       = o0;
        *((float4*)(orow + 4)) = o1;
    }
}

extern "C" void kernel_launch(void* const* d_in, const int* in_sizes, int n_in,
                              void* d_out, int out_size, void* d_ws, size_t ws_size,
                              hipStream_t stream) {
    const float* x    = (const float*)d_in[0];   // [8192][2048]
    const float* k    = (const float*)d_in[1];   // [2048][2048]
    const float* bias = (const float*)d_in[2];   // [2048]
    float* out = (float*)d_out;

    unsigned long long* xbits = (unsigned long long*)d_ws;                       // 2 MB
    unsigned long long* kbits = (unsigned long long*)((char*)d_ws + (size_t)B_DIM * (D_DIM / 8)); // 0.5 MB

    pack_x_kernel<<<(B_DIM * D_DIM) / 1024, 256, 0, stream>>>(x, xbits);
    pack_k_kernel<<<32 * 32, 256, 0, stream>>>(k, kbits);
    dim3 grid(U_DIM / 128, B_DIM / 128);
    bgemm_kernel<<<grid, 512, 0, stream>>>((const unsigned int*)xbits,
                                           (const unsigned int*)kbits, bias, out);
}